// Round 11
// baseline (695.253 us; speedup 1.0000x reference)
//
#include <hip/hip_runtime.h>
#include <hip/hip_bf16.h>

#define NSEG 128
#define H64 64
#define C1 256   // 4H
#define K1 128   // 2H
#define C2 64    // H
#define EPSV 1e-5f
#define NWG 256  // blocks for heavy kernels (1 per CU)

typedef __attribute__((ext_vector_type(8))) short bf16x8;
typedef __attribute__((ext_vector_type(16))) float f32x16;
typedef __attribute__((ext_vector_type(4))) unsigned int u32x4;

struct BTrue  { static constexpr bool value = true; };
struct BFalse { static constexpr bool value = false; };

__device__ __forceinline__ unsigned short f2bf(float f){
  unsigned int x = __float_as_uint(f);
  x += 0x7fffu + ((x >> 16) & 1u);   // RNE
  return (unsigned short)(x >> 16);
}
__device__ __forceinline__ float bf2f(unsigned short u){
  return __uint_as_float(((unsigned int)u) << 16);
}
__device__ __forceinline__ unsigned pkbf(float lo, float hi){
  unsigned r;
  asm("v_cvt_pk_bf16_f32 %0, %1, %2" : "=v"(r) : "v"(lo), "v"(hi));
  return r;
}
__device__ __forceinline__ bf16x8 mk8(unsigned a, unsigned b, unsigned c, unsigned d){
  u32x4 t = {a, b, c, d};
  return __builtin_bit_cast(bf16x8, t);
}
// bijective XCD swizzle (m204)
__device__ __forceinline__ int xcd_swz(int bid, int nwg){
  int q = nwg >> 3, r = nwg & 7;
  int x = bid & 7, o = bid >> 3;
  return (x < r ? x * (q + 1) : r * (q + 1) + (x - r) * q) + o;
}

// ---------------- prep (merged emb + weight conversion) ----------------
__global__ void k_cvt(const float* __restrict__ emb, const float* __restrict__ W1,
                      const float* __restrict__ W2, unsigned short* __restrict__ ebf,
                      unsigned short* __restrict__ W1T, unsigned short* __restrict__ W2T,
                      int n4){
  int i = blockIdx.x * blockDim.x + threadIdx.x;
  if (i < n4){
    float4 v = ((const float4*)emb)[i];
    unsigned int a = (unsigned int)f2bf(v.x) | ((unsigned int)f2bf(v.y) << 16);
    unsigned int b = (unsigned int)f2bf(v.z) | ((unsigned int)f2bf(v.w) << 16);
    ((uint2*)ebf)[i] = make_uint2(a, b);
    return;
  }
  int ip = i - n4;
  if (ip < C1 * K1){                      // W1T[c][k] = W1[k][c]
    int c = ip >> 7, k = ip & 127;
    W1T[ip] = f2bf(W1[k * C1 + c]);
  } else {
    int j = ip - C1 * K1;
    if (j < C2 * C1){                     // W2T[c][k] = W2[k][c]
      int c = j >> 8, k = j & 255;
      W2T[j] = f2bf(W2[k * C2 + c]);
    }
  }
}

// ---------------- counting sort by segment ----------------
__global__ void k_hist(const int* __restrict__ col, const int* __restrict__ batch,
                       int* __restrict__ segE, int* __restrict__ cnt, int E){
  __shared__ int h[NSEG];
  for (int i = threadIdx.x; i < NSEG; i += blockDim.x) h[i] = 0;
  __syncthreads();
  int stride = gridDim.x * blockDim.x;
  for (int e = blockIdx.x * blockDim.x + threadIdx.x; e < E; e += stride){
    int s = batch[col[e]];
    segE[e] = s;
    atomicAdd(&h[s], 1);
  }
  __syncthreads();
  for (int i = threadIdx.x; i < NSEG; i += blockDim.x)
    if (h[i]) atomicAdd(&cnt[i], h[i]);
}

__global__ void k_scan(const int* __restrict__ cnt, int* __restrict__ cursor,
                       float* __restrict__ cntf){
  if (threadIdx.x == 0){
    int acc = 0;
    for (int i = 0; i < NSEG; i++){ cursor[i] = acc; acc += cnt[i]; }
  }
  if (threadIdx.x < NSEG){
    int c = cnt[threadIdx.x];
    cntf[threadIdx.x] = (float)(c > 0 ? c : 1);
  }
}

__global__ void k_scatter(const int* __restrict__ segE, const int* __restrict__ ei,
                          int* __restrict__ cursor, int* __restrict__ perm,
                          int* __restrict__ segS, int* __restrict__ ecol, int* __restrict__ erow,
                          int* __restrict__ invp, int E, int epb){
  __shared__ int h[NSEG];
  __shared__ int base[NSEG];
  int b0 = blockIdx.x * epb;
  int b1 = b0 + epb < E ? b0 + epb : E;
  for (int i = threadIdx.x; i < NSEG; i += blockDim.x) h[i] = 0;
  __syncthreads();
  for (int e = b0 + threadIdx.x; e < b1; e += blockDim.x) atomicAdd(&h[segE[e]], 1);
  __syncthreads();
  for (int i = threadIdx.x; i < NSEG; i += blockDim.x)
    base[i] = h[i] ? atomicAdd(&cursor[i], h[i]) : 0;
  __syncthreads();
  for (int i = threadIdx.x; i < NSEG; i += blockDim.x) h[i] = 0;
  __syncthreads();
  for (int e = b0 + threadIdx.x; e < b1; e += blockDim.x){
    int s = segE[e];
    int p = base[s] + atomicAdd(&h[s], 1);
    perm[p] = e; segS[p] = s;
    ecol[p] = ei[e]; erow[p] = ei[(size_t)E + e];
    invp[e] = p;
  }
}

// ---------------- pass 1: GEMM1 (unswapped, W1T in LDS) + per-(seg,ch) stats ----------------
// 64-edge wave tiles; each LDS W-read feeds TWO edge-half MFMA chains (halved LDS traffic)
__global__ void __launch_bounds__(1024, 4)
k_stats1(const unsigned short* __restrict__ ebf, const unsigned short* __restrict__ W1T,
         const int* __restrict__ ecol, const int* __restrict__ erow, const int* __restrict__ segS,
         float* __restrict__ sum1, float* __restrict__ sq1, int NWT, int E, int T)
{
  __shared__ __align__(16) char wl[65536];     // W1T[256][128] bf16, unit^=(row&15)
  {
    #pragma unroll
    for (int j = 0; j < 4; j++){
      int i = threadIdx.x + j * 1024;          // 4096 16B-units
      int r = i >> 4, u = i & 15;
      u32x4 v = *(const u32x4*)(W1T + (size_t)r * K1 + u * 8);
      *(u32x4*)(wl + r * 256 + ((u ^ (r & 15)) << 4)) = v;
    }
  }
  __syncthreads();

  const int lane = threadIdx.x & 63, w = threadIdx.x >> 6;
  const int g = lane >> 5, l31 = lane & 31;
  const int bid = xcd_swz(blockIdx.x, NWG);
  const int wt0 = (bid * 16 + w) * T;
  float psum[8] = {0,0,0,0,0,0,0,0}, psq[8] = {0,0,0,0,0,0,0,0};
  int cur = -1;

  auto flush = [&](int seg){
    if (seg < 0) return;
    #pragma unroll
    for (int nt = 0; nt < 8; nt++){
      float sv = psum[nt] + __shfl_xor(psum[nt], 32);
      float qv = psq[nt]  + __shfl_xor(psq[nt], 32);
      if (lane < 32){
        atomicAdd(&sum1[seg * C1 + nt * 32 + l31], sv);
        atomicAdd(&sq1 [seg * C1 + nt * 32 + l31], qv);
      }
      psum[nt] = 0.f; psq[nt] = 0.f;
    }
  };

  for (int it = 0; it < T; ++it){
    int wt = wt0 + it;
    if (wt >= NWT) break;
    const int p0 = wt * 64;
    int e0 = p0 + l31, e1 = p0 + 32 + l31;
    int e0c = e0 < E ? e0 : E - 1, e1c = e1 < E ? e1 : E - 1;
    int cA = ecol[e0c], rA = erow[e0c], sg0 = segS[e0c];
    int cB = ecol[e1c], rB = erow[e1c], sg1 = segS[e1c];

    // A-frags for both edge halves: f12[edge][k = (2kk+g)*8 .. +7]
    bf16x8 fa[2][8];
    #pragma unroll
    for (int kk = 0; kk < 8; kk++){
      int off = (kk & 3) * 16 + g * 8;
      fa[0][kk] = *(const bf16x8*)(ebf + (size_t)(kk < 4 ? cA : rA) * H64 + off);
      fa[1][kk] = *(const bf16x8*)(ebf + (size_t)(kk < 4 ? cB : rB) * H64 + off);
    }

    int sA = __builtin_amdgcn_readfirstlane(__shfl(sg0, 0));
    int sB = __builtin_amdgcn_readfirstlane(__shfl(sg1, 31));
    bool uni = (sA == sB) && (p0 + 64 <= E);
    if (uni && sA != cur){ flush(cur); cur = sA; }
    if (!uni){ flush(cur); cur = -1; }

    #pragma unroll 1
    for (int nt = 0; nt < 8; nt++){
      f32x16 a0, a1;
      #pragma unroll
      for (int r = 0; r < 16; r++){ a0[r] = 0.f; a1[r] = 0.f; }
      const int rw = nt * 32 + l31;
      __builtin_amdgcn_s_setprio(1);
      #pragma unroll
      for (int kk = 0; kk < 8; kk++){
        bf16x8 b = *(const bf16x8*)(wl + rw * 256 + (((2 * kk + g) ^ (rw & 15)) << 4));
        a0 = __builtin_amdgcn_mfma_f32_32x32x16_bf16(fa[0][kk], b, a0, 0, 0, 0);
        a1 = __builtin_amdgcn_mfma_f32_32x32x16_bf16(fa[1][kk], b, a1, 0, 0, 0);
      }
      __builtin_amdgcn_s_setprio(0);
      if (uni){
        float ts = 0.f, tq = 0.f;
        #pragma unroll
        for (int r = 0; r < 16; r++){
          ts += a0[r] + a1[r];
          tq += a0[r] * a0[r] + a1[r] * a1[r];
        }
        psum[nt] += ts; psq[nt] += tq;
      } else {
        for (int s = sA; s <= sB; s++){
          float ts = 0.f, tq = 0.f;
          #pragma unroll
          for (int r = 0; r < 16; r++){
            int c = (r & 3) + 8 * (r >> 2) + 4 * g;
            bool ok0 = (__shfl(sg0, c) == s) && (p0 + c < E);
            bool ok1 = (__shfl(sg1, c) == s) && (p0 + 32 + c < E);
            float v0 = ok0 ? a0[r] : 0.f;
            float v1 = ok1 ? a1[r] : 0.f;
            ts += v0 + v1; tq += v0 * v0 + v1 * v1;
          }
          float sv = ts + __shfl_xor(ts, 32);
          float qv = tq + __shfl_xor(tq, 32);
          if (lane < 32){
            atomicAdd(&sum1[s * C1 + nt * 32 + l31], sv);
            atomicAdd(&sq1 [s * C1 + nt * 32 + l31], qv);
          }
        }
      }
    }
  }
  flush(cur);
}

// ---------------- finalize stats -> scale/shift ----------------
__global__ void k_fin(const float* __restrict__ sum, const float* __restrict__ sq,
                      const float* __restrict__ cntf,
                      float* __restrict__ sc, float* __restrict__ sh, int C){
  int i = blockIdx.x * blockDim.x + threadIdx.x;
  if (i >= NSEG * C) return;
  int s = i / C;
  float c = cntf[s];
  float m = sum[i] / c;
  float v = fmaxf(sq[i] / c - m * m, 0.f);
  float inv = rsqrtf(v + EPSV);
  sc[i] = inv;
  sh[i] = -m * inv;
}

// ---------------- pass 2: GEMM1(swapped) + norm1 + register-transpose + GEMM2(UNswapped) ----------------
// 32-edge wave tiles; per-wave sc1/sh1 LDS cache; idx prefetch.
// acc2 layout: D[edge rows][channel cols] -> lane owns channel ct*32+l31 => per-lane stats2 (free).
// MODE 0: store y2 + stats2 ; MODE 1: stats2 only (fallback) ; MODE 2: final output (fallback)
template<int MODE>
__global__ void __launch_bounds__(1024, 4)
k_mid(const unsigned short* __restrict__ ebf, const unsigned short* __restrict__ W1T,
      const unsigned short* __restrict__ W2T,
      const int* __restrict__ ecol, const int* __restrict__ erow,
      const int* __restrict__ segS, const int* __restrict__ perm,
      const float* __restrict__ sc1, const float* __restrict__ sh1,
      float* __restrict__ sum2, float* __restrict__ sq2,
      unsigned int* __restrict__ y2u,
      const float* __restrict__ sc2, const float* __restrict__ sh2,
      const float* __restrict__ W3, const float* __restrict__ b3,
      float* __restrict__ out, int NWT, int E, int T)
{
  __shared__ __align__(16) char wl[98304];   // [0,64K): W1T unit^=(r&15); [64K,96K): W2T unit^=(r&31)
  __shared__ __align__(16) float scsh[16][512];  // per-wave: [0..255]=sc1 row, [256..511]=sh1 row
  {
    #pragma unroll
    for (int j = 0; j < 4; j++){
      int i = threadIdx.x + j * 1024;
      int r = i >> 4, u = i & 15;
      u32x4 v = *(const u32x4*)(W1T + (size_t)r * K1 + u * 8);
      *(u32x4*)(wl + r * 256 + ((u ^ (r & 15)) << 4)) = v;
    }
    #pragma unroll
    for (int j = 0; j < 2; j++){
      int i = threadIdx.x + j * 1024;
      int r = i >> 5, u = i & 31;
      u32x4 v = *(const u32x4*)(W2T + (size_t)r * C1 + u * 8);
      *(u32x4*)(wl + 65536 + r * 512 + ((u ^ (r & 31)) << 4)) = v;
    }
  }
  __syncthreads();

  const int lane = threadIdx.x & 63, w = threadIdx.x >> 6;
  const int g = lane >> 5, l31 = lane & 31;
  const int bid = xcd_swz(blockIdx.x, NWG);
  const int wt0 = (bid * 16 + w) * T;

  float b3v = 0.f;
  if (MODE == 2) b3v = b3[0];
  int wseg = -1;   // seg currently cached in scsh[w]
  float ps2[2] = {0.f, 0.f}, pq2[2] = {0.f, 0.f};   // per-lane stats2 (channel ct*32+l31)
  int cur2 = -1;

  auto flush2 = [&](int seg){
    if (seg < 0) return;
    #pragma unroll
    for (int ct = 0; ct < 2; ct++){
      float sv = ps2[ct] + __shfl_xor(ps2[ct], 32);
      float qv = pq2[ct] + __shfl_xor(pq2[ct], 32);
      if (lane < 32){
        atomicAdd(&sum2[seg * C2 + ct * 32 + l31], sv);
        atomicAdd(&sq2 [seg * C2 + ct * 32 + l31], qv);
      }
      ps2[ct] = 0.f; pq2[ct] = 0.f;
    }
  };

  // 32-edge tile: GEMM1->norm->pack->GEMM2 (low register pressure)
  auto body = [&](auto uni_c, const bf16x8* fbp, int sgn, f32x16* acc2){
    constexpr bool UNI = decltype(uni_c)::value;
    #pragma unroll 1
    for (int mt = 0; mt < 8; mt++){
      f32x16 a1;
      #pragma unroll
      for (int r = 0; r < 16; r++) a1[r] = 0.f;
      const int rw = mt * 32 + l31;
      __builtin_amdgcn_s_setprio(1);
      #pragma unroll
      for (int kk = 0; kk < 8; kk++){
        bf16x8 wa = *(const bf16x8*)(wl + rw * 256 + (((2 * kk + g) ^ (rw & 15)) << 4));
        a1 = __builtin_amdgcn_mfma_f32_32x32x16_bf16(wa, fbp[kk], a1, 0, 0, 0);
      }
      __builtin_amdgcn_s_setprio(0);
      unsigned pk_[8];
      #pragma unroll
      for (int rq = 0; rq < 4; rq++){
        float4 sc, sh;
        if constexpr (UNI){
          sc = *(const float4*)(&scsh[w][mt * 32 + rq * 8 + 4 * g]);        // LDS broadcast
          sh = *(const float4*)(&scsh[w][256 + mt * 32 + rq * 8 + 4 * g]);
        } else {
          sc = *(const float4*)(sc1 + sgn * C1 + mt * 32 + rq * 8 + 4 * g);
          sh = *(const float4*)(sh1 + sgn * C1 + mt * 32 + rq * 8 + 4 * g);
        }
        float h0 = fmaxf(fmaf(a1[rq * 4 + 0], sc.x, sh.x), 0.f);
        float h1 = fmaxf(fmaf(a1[rq * 4 + 1], sc.y, sh.y), 0.f);
        float h2 = fmaxf(fmaf(a1[rq * 4 + 2], sc.z, sh.z), 0.f);
        float h3 = fmaxf(fmaf(a1[rq * 4 + 3], sc.w, sh.w), 0.f);
        pk_[rq * 2 + 0] = pkbf(h0, h1);
        pk_[rq * 2 + 1] = pkbf(h2, h3);
      }
      // register transpose: exchange complementary quads across lane-halves
      asm("v_permlane32_swap_b32 %0, %1" : "+v"(pk_[0]), "+v"(pk_[2]));
      asm("v_permlane32_swap_b32 %0, %1" : "+v"(pk_[1]), "+v"(pk_[3]));
      asm("v_permlane32_swap_b32 %0, %1" : "+v"(pk_[4]), "+v"(pk_[6]));
      asm("v_permlane32_swap_b32 %0, %1" : "+v"(pk_[5]), "+v"(pk_[7]));
      bf16x8 bf0 = mk8(pk_[0], pk_[1], pk_[2], pk_[3]);   // k = mt*32 + [0,16)
      bf16x8 bf1 = mk8(pk_[4], pk_[5], pk_[6], pk_[7]);   // k = mt*32 + [16,32)
      __builtin_amdgcn_s_setprio(1);
      #pragma unroll
      for (int ct = 0; ct < 2; ct++){
        int rb = ct * 32 + l31;
        bf16x8 wb0 = *(const bf16x8*)(wl + 65536 + rb * 512 + (((4 * mt + g) ^ (rb & 31)) << 4));
        bf16x8 wb1 = *(const bf16x8*)(wl + 65536 + rb * 512 + (((4 * mt + 2 + g) ^ (rb & 31)) << 4));
        // UNswapped: A = h1 frag (lane=edge row), B = W2T frag (lane=c2 col)
        acc2[ct] = __builtin_amdgcn_mfma_f32_32x32x16_bf16(bf0, wb0, acc2[ct], 0, 0, 0);
        acc2[ct] = __builtin_amdgcn_mfma_f32_32x32x16_bf16(bf1, wb1, acc2[ct], 0, 0, 0);
      }
      __builtin_amdgcn_s_setprio(0);
    }
  };

  auto ld3 = [&](int wt, int& a, int& r, int& s){
    int e = wt * 32 + l31;
    int ec = e < E ? e : E - 1;
    a = ecol[ec]; r = erow[ec]; s = segS[ec];
  };

  int cA, rA, sg;
  if (wt0 < NWT) ld3(wt0, cA, rA, sg);

  for (int it = 0; it < T; ++it){
    int wt = wt0 + it;
    if (wt >= NWT) break;
    const int p0 = wt * 32;
    int nA, nR, nS;
    const bool hv = (it + 1 < T) && (wt + 1 < NWT);
    if (hv) ld3(wt + 1, nA, nR, nS);      // prefetch next-tile indices

    // f12 B-frags (per-lane gather, L2/L3-resident)
    bf16x8 fb[8];
    #pragma unroll
    for (int kk = 0; kk < 8; kk++){
      int off = (kk & 3) * 16 + g * 8;
      fb[kk] = *(const bf16x8*)(ebf + (size_t)(kk < 4 ? cA : rA) * H64 + off);
    }

    int sA = __builtin_amdgcn_readfirstlane(__shfl(sg, 0));
    int sB = __builtin_amdgcn_readfirstlane(__shfl(sg, 31));
    const bool uni = (sA == sB) && (p0 + 32 <= E);

    if (uni && sA != wseg){                 // refill per-wave sc/sh cache (rare)
      float4 s4 = *(const float4*)(sc1 + sA * C1 + lane * 4);
      float4 h4 = *(const float4*)(sh1 + sA * C1 + lane * 4);
      *(float4*)(&scsh[w][lane * 4]) = s4;
      *(float4*)(&scsh[w][256 + lane * 4]) = h4;
      wseg = sA;
    }

    f32x16 acc2[2];
    #pragma unroll
    for (int ct = 0; ct < 2; ct++)
      #pragma unroll
      for (int r = 0; r < 16; r++) acc2[ct][r] = 0.f;

    if (uni) body(BTrue{},  fb, sg, acc2);
    else     body(BFalse{}, fb, sg, acc2);

    // ---- epilogue (acc2: row r -> edge (r&3)+8*(r>>2)+4g, col l31 -> channel ct*32+l31) ----
    if constexpr (MODE < 2){
      if constexpr (MODE == 0){
        unsigned short* y2s = (unsigned short*)y2u;
        #pragma unroll
        for (int ct = 0; ct < 2; ct++){
          int ch = ct * 32 + l31;
          #pragma unroll
          for (int r = 0; r < 16; r++){
            int eloc = (r & 3) + 8 * (r >> 2) + 4 * g;
            if (p0 + eloc < E)
              y2s[(size_t)(p0 + eloc) * C2 + ch] = f2bf(acc2[ct][r]);
          }
        }
      }
      if (uni){
        if (sA != cur2){ flush2(cur2); cur2 = sA; }
        #pragma unroll
        for (int ct = 0; ct < 2; ct++){
          float ts = 0.f, tq = 0.f;
          #pragma unroll
          for (int r = 0; r < 16; r++){ float x = acc2[ct][r]; ts += x; tq += x * x; }
          ps2[ct] += ts; pq2[ct] += tq;
        }
      } else {
        flush2(cur2); cur2 = -1;
        for (int s = sA; s <= sB; s++){
          #pragma unroll
          for (int ct = 0; ct < 2; ct++){
            float ts = 0.f, tq = 0.f;
            #pragma unroll
            for (int r = 0; r < 16; r++){
              int eloc = (r & 3) + 8 * (r >> 2) + 4 * g;
              bool ok = (__shfl(sg, eloc) == s) && (p0 + eloc < E);
              float x = ok ? acc2[ct][r] : 0.f;
              ts += x; tq += x * x;
            }
            float sv = ts + __shfl_xor(ts, 32);
            float qv = tq + __shfl_xor(tq, 32);
            if (lane < 32){
              atomicAdd(&sum2[s * C2 + ct * 32 + l31], sv);
              atomicAdd(&sq2 [s * C2 + ct * 32 + l31], qv);
            }
          }
        }
      }
    } else {
      // MODE 2 fallback: per-edge cross-lane reduce over channels
      #pragma unroll
      for (int r = 0; r < 16; r++){
        int eloc = (r & 3) + 8 * (r >> 2) + 4 * g;
        int sge = uni ? sA : __shfl(sg, eloc);
        float vtot = 0.f;
        #pragma unroll
        for (int ct = 0; ct < 2; ct++){
          int ch = ct * 32 + l31;
          float scv = sc2[sge * C2 + ch], shv = sh2[sge * C2 + ch];
          vtot += fmaxf(fmaf(acc2[ct][r], scv, shv), 0.f) * W3[ch];
        }
        vtot += __shfl_xor(vtot, 1); vtot += __shfl_xor(vtot, 2);
        vtot += __shfl_xor(vtot, 4); vtot += __shfl_xor(vtot, 8); vtot += __shfl_xor(vtot, 16);
        if (l31 == 0 && p0 + eloc < E) out[perm[p0 + eloc]] = vtot + b3v;
      }
    }
    if (hv){ cA = nA; rA = nR; sg = nS; }
  }
  if constexpr (MODE < 2) flush2(cur2);
}

// ---------------- pass 3: norm2 + relu + W3 dot -> tmp (sorted order, coalesced) ----------------
__global__ void k_out(const unsigned short* __restrict__ y2, const int* __restrict__ segS,
                      const float* __restrict__ sc2, const float* __restrict__ sh2,
                      const float* __restrict__ W3, const float* __restrict__ b3,
                      float* __restrict__ tmp, int E)
{
  const int lane = threadIdx.x & 63;
  const int wid = (blockIdx.x * blockDim.x + threadIdx.x) >> 6;
  const int nw = (gridDim.x * blockDim.x) >> 6;
  const int es = lane >> 3;        // edge sub-index within wave (0..7)
  const int cp = (lane & 7) * 8;   // channel base (8 per lane)
  float w3r[8];
  #pragma unroll
  for (int j = 0; j < 8; j++) w3r[j] = W3[cp + j];
  const float b3v = b3[0];
  for (long base = (long)wid * 8; base < E; base += (long)nw * 8){
    int pos = (int)base + es;
    float a = 0.f;
    if (pos < E){
      bf16x8 v = *(const bf16x8*)(y2 + (size_t)pos * C2 + cp);
      int s = segS[pos];
      const float* scp = sc2 + s * C2 + cp;
      const float* shp = sh2 + s * C2 + cp;
      #pragma unroll
      for (int j = 0; j < 8; j++){
        float hv = fmaxf(fmaf(bf2f((unsigned short)v[j]), scp[j], shp[j]), 0.f);
        a = fmaf(hv, w3r[j], a);
      }
    }
    a += __shfl_xor(a, 1); a += __shfl_xor(a, 2); a += __shfl_xor(a, 4);
    if ((lane & 7) == 0 && pos < E) tmp[pos] = a + b3v;
  }
}

// ---------------- pass 4: un-permute (coalesced read/write, L2-resident gather) ----------------
__global__ void k_remap(const float* __restrict__ tmp, const int* __restrict__ invp,
                        float* __restrict__ out, int E)
{
  int stride = gridDim.x * blockDim.x;
  for (int e = blockIdx.x * blockDim.x + threadIdx.x; e < E; e += stride)
    out[e] = tmp[invp[e]];
}

// ---------------- launch ----------------
extern "C" void kernel_launch(void* const* d_in, const int* in_sizes, int n_in,
                              void* d_out, int out_size, void* d_ws, size_t ws_size,
                              hipStream_t stream)
{
  const float* emb   = (const float*)d_in[0];
  const int*   ei    = (const int*)d_in[1];
  const int*   batch = (const int*)d_in[2];
  const float* W1    = (const float*)d_in[3];
  const float* W2    = (const float*)d_in[5];
  const float* W3    = (const float*)d_in[7];
  const float* b3    = (const float*)d_in[8];
  float* out = (float*)d_out;
  const int E = in_sizes[1] / 2;
  const int N = in_sizes[0] / H64;
  const int NWT  = (E + 31) / 32;           // 32-edge wave tiles (k_mid)
  const int NWT1 = (E + 63) / 64;           // 64-edge wave tiles (k_stats1)

  char* ws = (char*)d_ws;
  size_t o = 0;
  auto al = [&](size_t b){ size_t r = o; o = (o + b + 255) & ~((size_t)255); return r; };
  size_t o_ebf  = al((size_t)N * H64 * 2);
  size_t o_w1t  = al((size_t)C1 * K1 * 2);
  size_t o_w2t  = al((size_t)C2 * C1 * 2);
  size_t o_perm = al((size_t)E * 4);
  size_t o_segS = al((size_t)E * 4);
  size_t o_ecol = al((size_t)E * 4);
  size_t o_erow = al((size_t)E * 4);
  size_t o_invp = al((size_t)E * 4);
  size_t o_cnt  = al(NSEG * 4);
  size_t o_cur  = al(NSEG * 4);
  size_t o_cntf = al(NSEG * 4);
  size_t o_sum1 = al((size_t)NSEG * C1 * 4);
  size_t o_sq1  = al((size_t)NSEG * C1 * 4);
  size_t o_sum2 = al((size_t)NSEG * C2 * 4);
  size_t o_sq2  = al((size_t)NSEG * C2 * 4);
  size_t o_sc1  = al((size_t)NSEG * C1 * 4);
  size_t o_sh1  = al((size_t)NSEG * C1 * 4);
  size_t o_sc2  = al((size_t)NSEG * C2 * 4);
  size_t o_sh2  = al((size_t)NSEG * C2 * 4);
  size_t o_segE = al((size_t)E * 4);
  size_t o_y2   = o_segE;                 // y2 aliases segE (segE dead after sort)
  size_t need_full = o_segE + (size_t)E * C2 * 2;
  const bool full = ws_size >= need_full;

  unsigned short* ebf = (unsigned short*)(ws + o_ebf);
  unsigned short* W1T = (unsigned short*)(ws + o_w1t);
  unsigned short* W2T = (unsigned short*)(ws + o_w2t);
  int* perm = (int*)(ws + o_perm);
  int* segS = (int*)(ws + o_segS);
  int* ecol = (int*)(ws + o_ecol);
  int* erow = (int*)(ws + o_erow);
  int* invp = (int*)(ws + o_invp);
  int* cnt  = (int*)(ws + o_cnt);
  int* curp = (int*)(ws + o_cur);
  float* cntf = (float*)(ws + o_cntf);
  float* sum1 = (float*)(ws + o_sum1);
  float* sq1  = (float*)(ws + o_sq1);
  float* sum2 = (float*)(ws + o_sum2);
  float* sq2  = (float*)(ws + o_sq2);
  float* sc1  = (float*)(ws + o_sc1);
  float* sh1  = (float*)(ws + o_sh1);
  float* sc2  = (float*)(ws + o_sc2);
  float* sh2  = (float*)(ws + o_sh2);
  int* segE = (int*)(ws + o_segE);
  unsigned int* y2u = (unsigned int*)(ws + o_y2);
  unsigned short* y2 = (unsigned short*)(ws + o_y2);
  float* tmp = (float*)(ws + o_ecol);     // ecol dead after k_mid; reuse for tmp

  hipMemsetAsync(ws + o_cnt, 0, o_sc1 - o_cnt, stream);

  const int n4 = N * H64 / 4;
  k_cvt<<<(n4 + C1 * K1 + C2 * C1 + 255) / 256, 256, 0, stream>>>(emb, W1, W2, ebf, W1T, W2T, n4);

  k_hist<<<2048, 256, 0, stream>>>(ei, batch, segE, cnt, E);
  k_scan<<<1, 128, 0, stream>>>(cnt, curp, cntf);
  const int epb = 2048;
  k_scatter<<<(E + epb - 1) / epb, 256, 0, stream>>>(segE, ei, curp, perm, segS, ecol, erow, invp, E, epb);

  const int T1 = (NWT1 + NWG * 16 - 1) / (NWG * 16);
  k_stats1<<<NWG, 1024, 0, stream>>>(ebf, W1T, ecol, erow, segS, sum1, sq1, NWT1, E, T1);
  k_fin<<<(NSEG * C1) / 256, 256, 0, stream>>>(sum1, sq1, cntf, sc1, sh1, C1);

  const int T = (NWT + NWG * 16 - 1) / (NWG * 16);
  if (full){
    k_mid<0><<<NWG, 1024, 0, stream>>>(ebf, W1T, W2T, ecol, erow, segS, perm,
        sc1, sh1, sum2, sq2, y2u, sc2, sh2, W3, b3, out, NWT, E, T);
    k_fin<<<(NSEG * C2) / 256, 256, 0, stream>>>(sum2, sq2, cntf, sc2, sh2, C2);
    k_out<<<1024, 256, 0, stream>>>(y2, segS, sc2, sh2, W3, b3, tmp, E);
    k_remap<<<2048, 256, 0, stream>>>(tmp, invp, out, E);
  } else {
    k_mid<1><<<NWG, 1024, 0, stream>>>(ebf, W1T, W2T, ecol, erow, segS, perm,
        sc1, sh1, sum2, sq2, nullptr, sc2, sh2, W3, b3, out, NWT, E, T);
    k_fin<<<(NSEG * C2) / 256, 256, 0, stream>>>(sum2, sq2, cntf, sc2, sh2, C2);
    k_mid<2><<<NWG, 1024, 0, stream>>>(ebf, W1T, W2T, ecol, erow, segS, perm,
        sc1, sh1, sum2, sq2, nullptr, sc2, sh2, W3, b3, out, NWT, E, T);
  }
}

// Round 12
// 564.758 us; speedup vs baseline: 1.2311x; 1.2311x over previous
//
#include <hip/hip_runtime.h>
#include <hip/hip_bf16.h>

#define NSEG 128
#define H64 64
#define C1 256   // 4H
#define K1 128   // 2H
#define C2 64    // H
#define EPSV 1e-5f
#define NWG 256  // blocks for heavy kernels (1 per CU)

typedef __attribute__((ext_vector_type(8))) short bf16x8;
typedef __attribute__((ext_vector_type(16))) float f32x16;
typedef __attribute__((ext_vector_type(4))) unsigned int u32x4;

struct BTrue  { static constexpr bool value = true; };
struct BFalse { static constexpr bool value = false; };

__device__ __forceinline__ unsigned short f2bf(float f){
  unsigned int x = __float_as_uint(f);
  x += 0x7fffu + ((x >> 16) & 1u);   // RNE
  return (unsigned short)(x >> 16);
}
__device__ __forceinline__ float bf2f(unsigned short u){
  return __uint_as_float(((unsigned int)u) << 16);
}
__device__ __forceinline__ unsigned pkbf(float lo, float hi){
  unsigned r;
  asm("v_cvt_pk_bf16_f32 %0, %1, %2" : "=v"(r) : "v"(lo), "v"(hi));
  return r;
}
__device__ __forceinline__ bf16x8 mk8(unsigned a, unsigned b, unsigned c, unsigned d){
  u32x4 t = {a, b, c, d};
  return __builtin_bit_cast(bf16x8, t);
}
// bijective XCD swizzle (m204)
__device__ __forceinline__ int xcd_swz(int bid, int nwg){
  int q = nwg >> 3, r = nwg & 7;
  int x = bid & 7, o = bid >> 3;
  return (x < r ? x * (q + 1) : r * (q + 1) + (x - r) * q) + o;
}

// ---------------- prep (merged emb + weight conversion) ----------------
__global__ void k_cvt(const float* __restrict__ emb, const float* __restrict__ W1,
                      const float* __restrict__ W2, unsigned short* __restrict__ ebf,
                      unsigned short* __restrict__ W1T, unsigned short* __restrict__ W2T,
                      int n4){
  int i = blockIdx.x * blockDim.x + threadIdx.x;
  if (i < n4){
    float4 v = ((const float4*)emb)[i];
    unsigned int a = (unsigned int)f2bf(v.x) | ((unsigned int)f2bf(v.y) << 16);
    unsigned int b = (unsigned int)f2bf(v.z) | ((unsigned int)f2bf(v.w) << 16);
    ((uint2*)ebf)[i] = make_uint2(a, b);
    return;
  }
  int ip = i - n4;
  if (ip < C1 * K1){                      // W1T[c][k] = W1[k][c]
    int c = ip >> 7, k = ip & 127;
    W1T[ip] = f2bf(W1[k * C1 + c]);
  } else {
    int j = ip - C1 * K1;
    if (j < C2 * C1){                     // W2T[c][k] = W2[k][c]
      int c = j >> 8, k = j & 255;
      W2T[j] = f2bf(W2[k * C2 + c]);
    }
  }
}

// ---------------- counting sort by segment ----------------
__global__ void k_hist(const int* __restrict__ col, const int* __restrict__ batch,
                       int* __restrict__ segE, int* __restrict__ cnt, int E){
  __shared__ int h[NSEG];
  for (int i = threadIdx.x; i < NSEG; i += blockDim.x) h[i] = 0;
  __syncthreads();
  int stride = gridDim.x * blockDim.x;
  for (int e = blockIdx.x * blockDim.x + threadIdx.x; e < E; e += stride){
    int s = batch[col[e]];
    segE[e] = s;
    atomicAdd(&h[s], 1);
  }
  __syncthreads();
  for (int i = threadIdx.x; i < NSEG; i += blockDim.x)
    if (h[i]) atomicAdd(&cnt[i], h[i]);
}

__global__ void k_scan(const int* __restrict__ cnt, int* __restrict__ cursor,
                       float* __restrict__ cntf){
  if (threadIdx.x == 0){
    int acc = 0;
    for (int i = 0; i < NSEG; i++){ cursor[i] = acc; acc += cnt[i]; }
  }
  if (threadIdx.x < NSEG){
    int c = cnt[threadIdx.x];
    cntf[threadIdx.x] = (float)(c > 0 ? c : 1);
  }
}

__global__ void k_scatter(const int* __restrict__ segE, const int* __restrict__ ei,
                          int* __restrict__ cursor, int* __restrict__ perm,
                          int* __restrict__ segS, int* __restrict__ ecol, int* __restrict__ erow,
                          int* __restrict__ invp, int E, int epb){
  __shared__ int h[NSEG];
  __shared__ int base[NSEG];
  int b0 = blockIdx.x * epb;
  int b1 = b0 + epb < E ? b0 + epb : E;
  for (int i = threadIdx.x; i < NSEG; i += blockDim.x) h[i] = 0;
  __syncthreads();
  for (int e = b0 + threadIdx.x; e < b1; e += blockDim.x) atomicAdd(&h[segE[e]], 1);
  __syncthreads();
  for (int i = threadIdx.x; i < NSEG; i += blockDim.x)
    base[i] = h[i] ? atomicAdd(&cursor[i], h[i]) : 0;
  __syncthreads();
  for (int i = threadIdx.x; i < NSEG; i += blockDim.x) h[i] = 0;
  __syncthreads();
  for (int e = b0 + threadIdx.x; e < b1; e += blockDim.x){
    int s = segE[e];
    int p = base[s] + atomicAdd(&h[s], 1);
    perm[p] = e; segS[p] = s;
    ecol[p] = ei[e]; erow[p] = ei[(size_t)E + e];
    invp[e] = p;
  }
}

// ---------------- pass 1: GEMM1 (unswapped, W1T in LDS) + per-(seg,ch) stats ----------------
// 32-edge wave tiles; nt-unroll-2 (two independent MFMA chains); idx prefetch 1 tile ahead
__global__ void __launch_bounds__(1024, 4)
k_stats1(const unsigned short* __restrict__ ebf, const unsigned short* __restrict__ W1T,
         const int* __restrict__ ecol, const int* __restrict__ erow, const int* __restrict__ segS,
         float* __restrict__ sum1, float* __restrict__ sq1, int NWT, int E, int T)
{
  __shared__ __align__(16) char wl[65536];     // W1T[256][128] bf16, unit^=(row&15)
  {
    #pragma unroll
    for (int j = 0; j < 4; j++){
      int i = threadIdx.x + j * 1024;          // 4096 16B-units
      int r = i >> 4, u = i & 15;
      u32x4 v = *(const u32x4*)(W1T + (size_t)r * K1 + u * 8);
      *(u32x4*)(wl + r * 256 + ((u ^ (r & 15)) << 4)) = v;
    }
  }
  __syncthreads();

  const int lane = threadIdx.x & 63, w = threadIdx.x >> 6;
  const int g = lane >> 5, l31 = lane & 31;
  const int bid = xcd_swz(blockIdx.x, NWG);
  const int wt0 = (bid * 16 + w) * T;
  float psum[8] = {0,0,0,0,0,0,0,0}, psq[8] = {0,0,0,0,0,0,0,0};
  int cur = -1;

  auto flush = [&](int seg){
    if (seg < 0) return;
    #pragma unroll
    for (int nt = 0; nt < 8; nt++){
      float sv = psum[nt] + __shfl_xor(psum[nt], 32);
      float qv = psq[nt]  + __shfl_xor(psq[nt], 32);
      if (lane < 32){
        atomicAdd(&sum1[seg * C1 + nt * 32 + l31], sv);
        atomicAdd(&sq1 [seg * C1 + nt * 32 + l31], qv);
      }
      psum[nt] = 0.f; psq[nt] = 0.f;
    }
  };

  auto ld3 = [&](int wt, int& a, int& r, int& s){
    int e = wt * 32 + l31;
    int ec = e < E ? e : E - 1;
    a = ecol[ec]; r = erow[ec]; s = segS[ec];
  };

  int cA, rA, sg;
  if (wt0 < NWT) ld3(wt0, cA, rA, sg);

  for (int it = 0; it < T; ++it){
    int wt = wt0 + it;
    if (wt >= NWT) break;
    const int p0 = wt * 32;
    int nA, nR, nS;
    const bool hv = (it + 1 < T) && (wt + 1 < NWT);
    if (hv) ld3(wt + 1, nA, nR, nS);      // prefetch next-tile indices

    // A-frags: f12[edge = p0 + l31][k = (2kk+g)*8 .. +7]
    bf16x8 fa[8];
    #pragma unroll
    for (int kk = 0; kk < 8; kk++){
      int off = (kk & 3) * 16 + g * 8;
      fa[kk] = *(const bf16x8*)(ebf + (size_t)(kk < 4 ? cA : rA) * H64 + off);
    }

    int sA = __builtin_amdgcn_readfirstlane(__shfl(sg, 0));
    int sB = __builtin_amdgcn_readfirstlane(__shfl(sg, 31));
    bool uni = (sA == sB) && (p0 + 32 <= E);
    if (uni && sA != cur){ flush(cur); cur = sA; }
    if (!uni){ flush(cur); cur = -1; }

    #pragma unroll 1
    for (int np = 0; np < 4; np++){
      const int nt0 = 2 * np, nt1 = 2 * np + 1;
      f32x16 a0, a1;
      #pragma unroll
      for (int r = 0; r < 16; r++){ a0[r] = 0.f; a1[r] = 0.f; }
      const int rw0 = nt0 * 32 + l31, rw1 = nt1 * 32 + l31;
      __builtin_amdgcn_s_setprio(1);
      #pragma unroll
      for (int kk = 0; kk < 8; kk++){
        bf16x8 b0 = *(const bf16x8*)(wl + rw0 * 256 + (((2 * kk + g) ^ (rw0 & 15)) << 4));
        bf16x8 b1 = *(const bf16x8*)(wl + rw1 * 256 + (((2 * kk + g) ^ (rw1 & 15)) << 4));
        a0 = __builtin_amdgcn_mfma_f32_32x32x16_bf16(fa[kk], b0, a0, 0, 0, 0);
        a1 = __builtin_amdgcn_mfma_f32_32x32x16_bf16(fa[kk], b1, a1, 0, 0, 0);
      }
      __builtin_amdgcn_s_setprio(0);
      if (uni){
        float t0 = 0.f, q0 = 0.f, t1 = 0.f, q1 = 0.f;
        #pragma unroll
        for (int r = 0; r < 16; r++){
          t0 += a0[r]; q0 += a0[r] * a0[r];
          t1 += a1[r]; q1 += a1[r] * a1[r];
        }
        psum[nt0] += t0; psq[nt0] += q0;
        psum[nt1] += t1; psq[nt1] += q1;
      } else {
        for (int s = sA; s <= sB; s++){
          float t0 = 0.f, q0 = 0.f, t1 = 0.f, q1 = 0.f;
          #pragma unroll
          for (int r = 0; r < 16; r++){
            int c = (r & 3) + 8 * (r >> 2) + 4 * g;
            bool ok = (__shfl(sg, c) == s) && (p0 + c < E);
            float v0 = ok ? a0[r] : 0.f;
            float v1 = ok ? a1[r] : 0.f;
            t0 += v0; q0 += v0 * v0;
            t1 += v1; q1 += v1 * v1;
          }
          float s0 = t0 + __shfl_xor(t0, 32);
          float qq0 = q0 + __shfl_xor(q0, 32);
          float s1 = t1 + __shfl_xor(t1, 32);
          float qq1 = q1 + __shfl_xor(q1, 32);
          if (lane < 32){
            atomicAdd(&sum1[s * C1 + nt0 * 32 + l31], s0);
            atomicAdd(&sq1 [s * C1 + nt0 * 32 + l31], qq0);
            atomicAdd(&sum1[s * C1 + nt1 * 32 + l31], s1);
            atomicAdd(&sq1 [s * C1 + nt1 * 32 + l31], qq1);
          }
        }
      }
    }
    if (hv){ cA = nA; rA = nR; sg = nS; }
  }
  flush(cur);
}

// ---------------- finalize stats -> scale/shift ----------------
__global__ void k_fin(const float* __restrict__ sum, const float* __restrict__ sq,
                      const float* __restrict__ cntf,
                      float* __restrict__ sc, float* __restrict__ sh, int C){
  int i = blockIdx.x * blockDim.x + threadIdx.x;
  if (i >= NSEG * C) return;
  int s = i / C;
  float c = cntf[s];
  float m = sum[i] / c;
  float v = fmaxf(sq[i] / c - m * m, 0.f);
  float inv = rsqrtf(v + EPSV);
  sc[i] = inv;
  sh[i] = -m * inv;
}

// ---------------- pass 2: GEMM1(swapped) + norm1 + register-transpose + GEMM2(UNswapped) ----------------
// 32-edge wave tiles; per-wave sc1/sh1 LDS cache; idx prefetch.
// acc2 layout: D[edge rows][channel cols] -> lane owns channel ct*32+l31 => per-lane stats2 (free).
// MODE 0: store y2 + stats2 ; MODE 1: stats2 only (fallback) ; MODE 2: final output (fallback)
template<int MODE>
__global__ void __launch_bounds__(1024, 4)
k_mid(const unsigned short* __restrict__ ebf, const unsigned short* __restrict__ W1T,
      const unsigned short* __restrict__ W2T,
      const int* __restrict__ ecol, const int* __restrict__ erow,
      const int* __restrict__ segS, const int* __restrict__ perm,
      const float* __restrict__ sc1, const float* __restrict__ sh1,
      float* __restrict__ sum2, float* __restrict__ sq2,
      unsigned int* __restrict__ y2u,
      const float* __restrict__ sc2, const float* __restrict__ sh2,
      const float* __restrict__ W3, const float* __restrict__ b3,
      float* __restrict__ out, int NWT, int E, int T)
{
  __shared__ __align__(16) char wl[98304];   // [0,64K): W1T unit^=(r&15); [64K,96K): W2T unit^=(r&31)
  __shared__ __align__(16) float scsh[16][512];  // per-wave: [0..255]=sc1 row, [256..511]=sh1 row
  {
    #pragma unroll
    for (int j = 0; j < 4; j++){
      int i = threadIdx.x + j * 1024;
      int r = i >> 4, u = i & 15;
      u32x4 v = *(const u32x4*)(W1T + (size_t)r * K1 + u * 8);
      *(u32x4*)(wl + r * 256 + ((u ^ (r & 15)) << 4)) = v;
    }
    #pragma unroll
    for (int j = 0; j < 2; j++){
      int i = threadIdx.x + j * 1024;
      int r = i >> 5, u = i & 31;
      u32x4 v = *(const u32x4*)(W2T + (size_t)r * C1 + u * 8);
      *(u32x4*)(wl + 65536 + r * 512 + ((u ^ (r & 31)) << 4)) = v;
    }
  }
  __syncthreads();

  const int lane = threadIdx.x & 63, w = threadIdx.x >> 6;
  const int g = lane >> 5, l31 = lane & 31;
  const int bid = xcd_swz(blockIdx.x, NWG);
  const int wt0 = (bid * 16 + w) * T;

  float b3v = 0.f;
  if (MODE == 2) b3v = b3[0];
  int wseg = -1;   // seg currently cached in scsh[w]
  float ps2[2] = {0.f, 0.f}, pq2[2] = {0.f, 0.f};   // per-lane stats2 (channel ct*32+l31)
  int cur2 = -1;

  auto flush2 = [&](int seg){
    if (seg < 0) return;
    #pragma unroll
    for (int ct = 0; ct < 2; ct++){
      float sv = ps2[ct] + __shfl_xor(ps2[ct], 32);
      float qv = pq2[ct] + __shfl_xor(pq2[ct], 32);
      if (lane < 32){
        atomicAdd(&sum2[seg * C2 + ct * 32 + l31], sv);
        atomicAdd(&sq2 [seg * C2 + ct * 32 + l31], qv);
      }
      ps2[ct] = 0.f; pq2[ct] = 0.f;
    }
  };

  // 32-edge tile: GEMM1->norm->pack->GEMM2 (low register pressure)
  auto body = [&](auto uni_c, const bf16x8* fbp, int sgn, f32x16* acc2){
    constexpr bool UNI = decltype(uni_c)::value;
    #pragma unroll 1
    for (int mt = 0; mt < 8; mt++){
      f32x16 a1;
      #pragma unroll
      for (int r = 0; r < 16; r++) a1[r] = 0.f;
      const int rw = mt * 32 + l31;
      __builtin_amdgcn_s_setprio(1);
      #pragma unroll
      for (int kk = 0; kk < 8; kk++){
        bf16x8 wa = *(const bf16x8*)(wl + rw * 256 + (((2 * kk + g) ^ (rw & 15)) << 4));
        a1 = __builtin_amdgcn_mfma_f32_32x32x16_bf16(wa, fbp[kk], a1, 0, 0, 0);
      }
      __builtin_amdgcn_s_setprio(0);
      unsigned pk_[8];
      #pragma unroll
      for (int rq = 0; rq < 4; rq++){
        float4 sc, sh;
        if constexpr (UNI){
          sc = *(const float4*)(&scsh[w][mt * 32 + rq * 8 + 4 * g]);        // LDS broadcast
          sh = *(const float4*)(&scsh[w][256 + mt * 32 + rq * 8 + 4 * g]);
        } else {
          sc = *(const float4*)(sc1 + sgn * C1 + mt * 32 + rq * 8 + 4 * g);
          sh = *(const float4*)(sh1 + sgn * C1 + mt * 32 + rq * 8 + 4 * g);
        }
        float h0 = fmaxf(fmaf(a1[rq * 4 + 0], sc.x, sh.x), 0.f);
        float h1 = fmaxf(fmaf(a1[rq * 4 + 1], sc.y, sh.y), 0.f);
        float h2 = fmaxf(fmaf(a1[rq * 4 + 2], sc.z, sh.z), 0.f);
        float h3 = fmaxf(fmaf(a1[rq * 4 + 3], sc.w, sh.w), 0.f);
        pk_[rq * 2 + 0] = pkbf(h0, h1);
        pk_[rq * 2 + 1] = pkbf(h2, h3);
      }
      // register transpose: exchange complementary quads across lane-halves
      asm("v_permlane32_swap_b32 %0, %1" : "+v"(pk_[0]), "+v"(pk_[2]));
      asm("v_permlane32_swap_b32 %0, %1" : "+v"(pk_[1]), "+v"(pk_[3]));
      asm("v_permlane32_swap_b32 %0, %1" : "+v"(pk_[4]), "+v"(pk_[6]));
      asm("v_permlane32_swap_b32 %0, %1" : "+v"(pk_[5]), "+v"(pk_[7]));
      bf16x8 bf0 = mk8(pk_[0], pk_[1], pk_[2], pk_[3]);   // k = mt*32 + [0,16)
      bf16x8 bf1 = mk8(pk_[4], pk_[5], pk_[6], pk_[7]);   // k = mt*32 + [16,32)
      __builtin_amdgcn_s_setprio(1);
      #pragma unroll
      for (int ct = 0; ct < 2; ct++){
        int rb = ct * 32 + l31;
        bf16x8 wb0 = *(const bf16x8*)(wl + 65536 + rb * 512 + (((4 * mt + g) ^ (rb & 31)) << 4));
        bf16x8 wb1 = *(const bf16x8*)(wl + 65536 + rb * 512 + (((4 * mt + 2 + g) ^ (rb & 31)) << 4));
        // UNswapped: A = h1 frag (lane=edge row), B = W2T frag (lane=c2 col)
        acc2[ct] = __builtin_amdgcn_mfma_f32_32x32x16_bf16(bf0, wb0, acc2[ct], 0, 0, 0);
        acc2[ct] = __builtin_amdgcn_mfma_f32_32x32x16_bf16(bf1, wb1, acc2[ct], 0, 0, 0);
      }
      __builtin_amdgcn_s_setprio(0);
    }
  };

  auto ld3 = [&](int wt, int& a, int& r, int& s){
    int e = wt * 32 + l31;
    int ec = e < E ? e : E - 1;
    a = ecol[ec]; r = erow[ec]; s = segS[ec];
  };

  int cA, rA, sg;
  if (wt0 < NWT) ld3(wt0, cA, rA, sg);

  for (int it = 0; it < T; ++it){
    int wt = wt0 + it;
    if (wt >= NWT) break;
    const int p0 = wt * 32;
    int nA, nR, nS;
    const bool hv = (it + 1 < T) && (wt + 1 < NWT);
    if (hv) ld3(wt + 1, nA, nR, nS);      // prefetch next-tile indices

    // f12 B-frags (per-lane gather, L2/L3-resident)
    bf16x8 fb[8];
    #pragma unroll
    for (int kk = 0; kk < 8; kk++){
      int off = (kk & 3) * 16 + g * 8;
      fb[kk] = *(const bf16x8*)(ebf + (size_t)(kk < 4 ? cA : rA) * H64 + off);
    }

    int sA = __builtin_amdgcn_readfirstlane(__shfl(sg, 0));
    int sB = __builtin_amdgcn_readfirstlane(__shfl(sg, 31));
    const bool uni = (sA == sB) && (p0 + 32 <= E);

    if (uni && sA != wseg){                 // refill per-wave sc/sh cache (rare)
      float4 s4 = *(const float4*)(sc1 + sA * C1 + lane * 4);
      float4 h4 = *(const float4*)(sh1 + sA * C1 + lane * 4);
      *(float4*)(&scsh[w][lane * 4]) = s4;
      *(float4*)(&scsh[w][256 + lane * 4]) = h4;
      wseg = sA;
    }

    f32x16 acc2[2];
    #pragma unroll
    for (int ct = 0; ct < 2; ct++)
      #pragma unroll
      for (int r = 0; r < 16; r++) acc2[ct][r] = 0.f;

    if (uni) body(BTrue{},  fb, sg, acc2);
    else     body(BFalse{}, fb, sg, acc2);

    // ---- epilogue (acc2: row r -> edge (r&3)+8*(r>>2)+4g, col l31 -> channel ct*32+l31) ----
    if constexpr (MODE < 2){
      if constexpr (MODE == 0){
        unsigned short* y2s = (unsigned short*)y2u;
        #pragma unroll
        for (int ct = 0; ct < 2; ct++){
          int ch = ct * 32 + l31;
          #pragma unroll
          for (int r = 0; r < 16; r++){
            int eloc = (r & 3) + 8 * (r >> 2) + 4 * g;
            if (p0 + eloc < E)
              y2s[(size_t)(p0 + eloc) * C2 + ch] = f2bf(acc2[ct][r]);
          }
        }
      }
      if (uni){
        if (sA != cur2){ flush2(cur2); cur2 = sA; }
        #pragma unroll
        for (int ct = 0; ct < 2; ct++){
          float ts = 0.f, tq = 0.f;
          #pragma unroll
          for (int r = 0; r < 16; r++){ float x = acc2[ct][r]; ts += x; tq += x * x; }
          ps2[ct] += ts; pq2[ct] += tq;
        }
      } else {
        flush2(cur2); cur2 = -1;
        for (int s = sA; s <= sB; s++){
          #pragma unroll
          for (int ct = 0; ct < 2; ct++){
            float ts = 0.f, tq = 0.f;
            #pragma unroll
            for (int r = 0; r < 16; r++){
              int eloc = (r & 3) + 8 * (r >> 2) + 4 * g;
              bool ok = (__shfl(sg, eloc) == s) && (p0 + eloc < E);
              float x = ok ? acc2[ct][r] : 0.f;
              ts += x; tq += x * x;
            }
            float sv = ts + __shfl_xor(ts, 32);
            float qv = tq + __shfl_xor(tq, 32);
            if (lane < 32){
              atomicAdd(&sum2[s * C2 + ct * 32 + l31], sv);
              atomicAdd(&sq2 [s * C2 + ct * 32 + l31], qv);
            }
          }
        }
      }
    } else {
      // MODE 2 fallback: per-edge cross-lane reduce over channels
      #pragma unroll
      for (int r = 0; r < 16; r++){
        int eloc = (r & 3) + 8 * (r >> 2) + 4 * g;
        int sge = uni ? sA : __shfl(sg, eloc);
        float vtot = 0.f;
        #pragma unroll
        for (int ct = 0; ct < 2; ct++){
          int ch = ct * 32 + l31;
          float scv = sc2[sge * C2 + ch], shv = sh2[sge * C2 + ch];
          vtot += fmaxf(fmaf(acc2[ct][r], scv, shv), 0.f) * W3[ch];
        }
        vtot += __shfl_xor(vtot, 1); vtot += __shfl_xor(vtot, 2);
        vtot += __shfl_xor(vtot, 4); vtot += __shfl_xor(vtot, 8); vtot += __shfl_xor(vtot, 16);
        if (l31 == 0 && p0 + eloc < E) out[perm[p0 + eloc]] = vtot + b3v;
      }
    }
    if (hv){ cA = nA; rA = nR; sg = nS; }
  }
  if constexpr (MODE < 2) flush2(cur2);
}

// ---------------- pass 3: norm2 + relu + W3 dot -> tmp (sorted order, coalesced) ----------------
__global__ void k_out(const unsigned short* __restrict__ y2, const int* __restrict__ segS,
                      const float* __restrict__ sc2, const float* __restrict__ sh2,
                      const float* __restrict__ W3, const float* __restrict__ b3,
                      float* __restrict__ tmp, int E)
{
  const int lane = threadIdx.x & 63;
  const int wid = (blockIdx.x * blockDim.x + threadIdx.x) >> 6;
  const int nw = (gridDim.x * blockDim.x) >> 6;
  const int es = lane >> 3;        // edge sub-index within wave (0..7)
  const int cp = (lane & 7) * 8;   // channel base (8 per lane)
  float w3r[8];
  #pragma unroll
  for (int j = 0; j < 8; j++) w3r[j] = W3[cp + j];
  const float b3v = b3[0];
  for (long base = (long)wid * 8; base < E; base += (long)nw * 8){
    int pos = (int)base + es;
    float a = 0.f;
    if (pos < E){
      bf16x8 v = *(const bf16x8*)(y2 + (size_t)pos * C2 + cp);
      int s = segS[pos];
      const float* scp = sc2 + s * C2 + cp;
      const float* shp = sh2 + s * C2 + cp;
      #pragma unroll
      for (int j = 0; j < 8; j++){
        float hv = fmaxf(fmaf(bf2f((unsigned short)v[j]), scp[j], shp[j]), 0.f);
        a = fmaf(hv, w3r[j], a);
      }
    }
    a += __shfl_xor(a, 1); a += __shfl_xor(a, 2); a += __shfl_xor(a, 4);
    if ((lane & 7) == 0 && pos < E) tmp[pos] = a + b3v;
  }
}

// ---------------- pass 4: un-permute (coalesced read/write, L2-resident gather) ----------------
__global__ void k_remap(const float* __restrict__ tmp, const int* __restrict__ invp,
                        float* __restrict__ out, int E)
{
  int stride = gridDim.x * blockDim.x;
  for (int e = blockIdx.x * blockDim.x + threadIdx.x; e < E; e += stride)
    out[e] = tmp[invp[e]];
}

// ---------------- launch ----------------
extern "C" void kernel_launch(void* const* d_in, const int* in_sizes, int n_in,
                              void* d_out, int out_size, void* d_ws, size_t ws_size,
                              hipStream_t stream)
{
  const float* emb   = (const float*)d_in[0];
  const int*   ei    = (const int*)d_in[1];
  const int*   batch = (const int*)d_in[2];
  const float* W1    = (const float*)d_in[3];
  const float* W2    = (const float*)d_in[5];
  const float* W3    = (const float*)d_in[7];
  const float* b3    = (const float*)d_in[8];
  float* out = (float*)d_out;
  const int E = in_sizes[1] / 2;
  const int N = in_sizes[0] / H64;
  const int NWT = (E + 31) / 32;            // 32-edge wave tiles

  char* ws = (char*)d_ws;
  size_t o = 0;
  auto al = [&](size_t b){ size_t r = o; o = (o + b + 255) & ~((size_t)255); return r; };
  size_t o_ebf  = al((size_t)N * H64 * 2);
  size_t o_w1t  = al((size_t)C1 * K1 * 2);
  size_t o_w2t  = al((size_t)C2 * C1 * 2);
  size_t o_perm = al((size_t)E * 4);
  size_t o_segS = al((size_t)E * 4);
  size_t o_ecol = al((size_t)E * 4);
  size_t o_erow = al((size_t)E * 4);
  size_t o_invp = al((size_t)E * 4);
  size_t o_cnt  = al(NSEG * 4);
  size_t o_cur  = al(NSEG * 4);
  size_t o_cntf = al(NSEG * 4);
  size_t o_sum1 = al((size_t)NSEG * C1 * 4);
  size_t o_sq1  = al((size_t)NSEG * C1 * 4);
  size_t o_sum2 = al((size_t)NSEG * C2 * 4);
  size_t o_sq2  = al((size_t)NSEG * C2 * 4);
  size_t o_sc1  = al((size_t)NSEG * C1 * 4);
  size_t o_sh1  = al((size_t)NSEG * C1 * 4);
  size_t o_sc2  = al((size_t)NSEG * C2 * 4);
  size_t o_sh2  = al((size_t)NSEG * C2 * 4);
  size_t o_segE = al((size_t)E * 4);
  size_t o_y2   = o_segE;                 // y2 aliases segE (segE dead after sort)
  size_t need_full = o_segE + (size_t)E * C2 * 2;
  const bool full = ws_size >= need_full;

  unsigned short* ebf = (unsigned short*)(ws + o_ebf);
  unsigned short* W1T = (unsigned short*)(ws + o_w1t);
  unsigned short* W2T = (unsigned short*)(ws + o_w2t);
  int* perm = (int*)(ws + o_perm);
  int* segS = (int*)(ws + o_segS);
  int* ecol = (int*)(ws + o_ecol);
  int* erow = (int*)(ws + o_erow);
  int* invp = (int*)(ws + o_invp);
  int* cnt  = (int*)(ws + o_cnt);
  int* curp = (int*)(ws + o_cur);
  float* cntf = (float*)(ws + o_cntf);
  float* sum1 = (float*)(ws + o_sum1);
  float* sq1  = (float*)(ws + o_sq1);
  float* sum2 = (float*)(ws + o_sum2);
  float* sq2  = (float*)(ws + o_sq2);
  float* sc1  = (float*)(ws + o_sc1);
  float* sh1  = (float*)(ws + o_sh1);
  float* sc2  = (float*)(ws + o_sc2);
  float* sh2  = (float*)(ws + o_sh2);
  int* segE = (int*)(ws + o_segE);
  unsigned int* y2u = (unsigned int*)(ws + o_y2);
  unsigned short* y2 = (unsigned short*)(ws + o_y2);
  float* tmp = (float*)(ws + o_ecol);     // ecol dead after k_mid; reuse for tmp

  hipMemsetAsync(ws + o_cnt, 0, o_sc1 - o_cnt, stream);

  const int n4 = N * H64 / 4;
  k_cvt<<<(n4 + C1 * K1 + C2 * C1 + 255) / 256, 256, 0, stream>>>(emb, W1, W2, ebf, W1T, W2T, n4);

  k_hist<<<2048, 256, 0, stream>>>(ei, batch, segE, cnt, E);
  k_scan<<<1, 128, 0, stream>>>(cnt, curp, cntf);
  const int epb = 2048;
  k_scatter<<<(E + epb - 1) / epb, 256, 0, stream>>>(segE, ei, curp, perm, segS, ecol, erow, invp, E, epb);

  const int T = (NWT + NWG * 16 - 1) / (NWG * 16);
  k_stats1<<<NWG, 1024, 0, stream>>>(ebf, W1T, ecol, erow, segS, sum1, sq1, NWT, E, T);
  k_fin<<<(NSEG * C1) / 256, 256, 0, stream>>>(sum1, sq1, cntf, sc1, sh1, C1);

  if (full){
    k_mid<0><<<NWG, 1024, 0, stream>>>(ebf, W1T, W2T, ecol, erow, segS, perm,
        sc1, sh1, sum2, sq2, y2u, sc2, sh2, W3, b3, out, NWT, E, T);
    k_fin<<<(NSEG * C2) / 256, 256, 0, stream>>>(sum2, sq2, cntf, sc2, sh2, C2);
    k_out<<<1024, 256, 0, stream>>>(y2, segS, sc2, sh2, W3, b3, tmp, E);
    k_remap<<<2048, 256, 0, stream>>>(tmp, invp, out, E);
  } else {
    k_mid<1><<<NWG, 1024, 0, stream>>>(ebf, W1T, W2T, ecol, erow, segS, perm,
        sc1, sh1, sum2, sq2, nullptr, sc2, sh2, W3, b3, out, NWT, E, T);
    k_fin<<<(NSEG * C2) / 256, 256, 0, stream>>>(sum2, sq2, cntf, sc2, sh2, C2);
    k_mid<2><<<NWG, 1024, 0, stream>>>(ebf, W1T, W2T, ecol, erow, segS, perm,
        sc1, sh1, sum2, sq2, nullptr, sc2, sh2, W3, b3, out, NWT, E, T);
  }
}